// Round 8
// baseline (110.991 us; speedup 1.0000x reference)
//
#include <hip/hip_runtime.h>
#include <math.h>

#define D 256
#define NRULES 1024
#define TPB 8     // tokens per pass over a rule matrix
#define KMAX 16   // bucket stride; slot>=KMAX spills (P ~ 0 at Poisson(2))
#define NSPILLBLK 64

// ---------------- prep: parallel histogram, no scan ----------------
__global__ void prep_kernel(const int* __restrict__ token_ids,
                            const int* __restrict__ token_rules,
                            int ntok,
                            int* __restrict__ counts,   // [NRULES] pre-zeroed
                            int* __restrict__ bucket,   // [NRULES*KMAX]
                            int* __restrict__ spill,    // [ntok]
                            int* __restrict__ nspill) { // [1] pre-zeroed
    const int i = blockIdx.x * blockDim.x + threadIdx.x;
    if (i >= ntok) return;
    const int r = token_rules[token_ids[i]];
    const int slot = atomicAdd(&counts[r], 1);
    if (slot < KMAX) bucket[r * KMAX + slot] = i;
    else             spill[atomicAdd(nspill, 1)] = (r << 16) | i;
}

// ---------------- one full-matrix pass by a single wave ----------------
// Lane t owns cols [4t,4t+4). Each load = 1KB contiguous row. acc stays in
// registers for all 256 rows; Frobenius all-reduced via shfl_xor.
template <int CNT>
__device__ __forceinline__ void rule_pass(
    const float* __restrict__ M,
    const float (*__restrict__ h_lds)[D],
    const int* __restrict__ toks,   // LDS
    int c,                          // live tokens this pass (<= CNT)
    int t,
    float* __restrict__ out)
{
    const int c4 = t << 2;
    float4 acc[CNT];
    #pragma unroll
    for (int j = 0; j < CNT; ++j) acc[j] = float4{0.f, 0.f, 0.f, 0.f};
    float sqx = 0.f, sqy = 0.f, sqz = 0.f, sqw = 0.f;  // 4 chains, no serial stall

    #pragma unroll 8
    for (int d = 0; d < D; ++d) {
        const float4 m = *reinterpret_cast<const float4*>(M + (size_t)d * D + c4);
        sqx = fmaf(m.x, m.x, sqx);
        sqy = fmaf(m.y, m.y, sqy);
        sqz = fmaf(m.z, m.z, sqz);
        sqw = fmaf(m.w, m.w, sqw);
        #pragma unroll
        for (int j = 0; j < CNT; ++j) {
            const float h = h_lds[j][d];  // uniform addr -> LDS broadcast
            acc[j].x = fmaf(h, m.x, acc[j].x);
            acc[j].y = fmaf(h, m.y, acc[j].y);
            acc[j].z = fmaf(h, m.z, acc[j].z);
            acc[j].w = fmaf(h, m.w, acc[j].w);
        }
    }

    float sq = (sqx + sqy) + (sqz + sqw);
    #pragma unroll
    for (int mask = 1; mask < 64; mask <<= 1)
        sq += __shfl_xor(sq, mask, 64);               // all lanes get fro^2
    const float inv = 1.0f / fmaxf(sqrtf(sq), 1e-12f);

    #pragma unroll
    for (int j = 0; j < CNT; ++j) {
        if (j < c) {
            float4 o;
            o.x = acc[j].x * inv; o.y = acc[j].y * inv;
            o.z = acc[j].z * inv; o.w = acc[j].w * inv;
            *reinterpret_cast<float4*>(&out[(size_t)toks[j] * D + c4]) = o;  // 1KB contig
        }
    }
}

// ---------------- process: block b == rule b, ONE wave per block ----------------
__global__ __launch_bounds__(64) void process_kernel(
    const float* __restrict__ hidden,     // [NTOK, D]
    const float* __restrict__ rules,      // [NRULES, D, D]
    const int*   __restrict__ counts,
    const int*   __restrict__ bucket,
    const int*   __restrict__ spill,
    const int*   __restrict__ nspill,
    float* __restrict__ out)
{
    const int b = blockIdx.x;
    const int t = threadIdx.x;

    __shared__ float h_lds[TPB][D];
    __shared__ int   toks[TPB];

    if (b < NRULES) {
        const int cnt = min(counts[b], KMAX);
        if (cnt > 0) {
            const float* __restrict__ M = rules + (size_t)b * D * D;
            for (int base = 0; base < cnt; base += TPB) {
                const int c = min(cnt - base, TPB);
                if (t < c) toks[t] = bucket[b * KMAX + base + t];
                #pragma unroll
                for (int j = 0; j < TPB; ++j) {
                    float4 v = {0.f, 0.f, 0.f, 0.f};
                    if (j < c)
                        v = *reinterpret_cast<const float4*>(
                            &hidden[(size_t)bucket[b * KMAX + base + j] * D + (t << 2)]);
                    *reinterpret_cast<float4*>(&h_lds[j][t << 2]) = v;
                }
                __syncthreads();

                switch ((c == 1) ? 1 : (c == 2) ? 2 : (c <= 4) ? 4 : 8) {
                    case 1:  rule_pass<1>(M, h_lds, toks, c, t, out); break;
                    case 2:  rule_pass<2>(M, h_lds, toks, c, t, out); break;
                    case 4:  rule_pass<4>(M, h_lds, toks, c, t, out); break;
                    default: rule_pass<8>(M, h_lds, toks, c, t, out); break;
                }
                __syncthreads();  // protect h_lds before restage
            }
        }
    }

    // rare overflow tokens (count>KMAX): strided over all blocks, cnt=1 passes
    const int ns = nspill[0];
    for (int k = b; k < ns; k += gridDim.x) {
        __syncthreads();
        const int e   = spill[k];
        const int tok = e & 0xFFFF;
        const int r   = e >> 16;
        if (t == 0) toks[0] = tok;
        *reinterpret_cast<float4*>(&h_lds[0][t << 2]) =
            *reinterpret_cast<const float4*>(&hidden[(size_t)tok * D + (t << 2)]);
        __syncthreads();
        rule_pass<1>(rules + (size_t)r * D * D, h_lds, toks, 1, t, out);
    }
}

// ---------------- launcher ----------------
extern "C" void kernel_launch(void* const* d_in, const int* in_sizes, int n_in,
                              void* d_out, int out_size, void* d_ws, size_t ws_size,
                              hipStream_t stream) {
    const float* hidden      = (const float*)d_in[0];
    const int*   token_ids   = (const int*)d_in[1];
    const float* rules       = (const float*)d_in[2];
    const int*   token_rules = (const int*)d_in[3];
    float*       out         = (float*)d_out;

    const int ntok = in_sizes[1];  // B*S

    int* ws     = (int*)d_ws;
    int* counts = ws;                        // NRULES
    int* nspill = ws + NRULES;               // 1 (padded to 8)
    int* bucket = ws + NRULES + 8;           // NRULES*KMAX
    int* spill  = bucket + NRULES * KMAX;    // ntok

    hipMemsetAsync(counts, 0, (NRULES + 8) * sizeof(int), stream);
    prep_kernel<<<(ntok + 255) / 256, 256, 0, stream>>>(
        token_ids, token_rules, ntok, counts, bucket, spill, nspill);
    process_kernel<<<NRULES + NSPILLBLK, 64, 0, stream>>>(
        hidden, rules, counts, bucket, spill, nspill, out);
}

// Round 9
// 85.996 us; speedup vs baseline: 1.2906x; 1.2906x over previous
//
#include <hip/hip_runtime.h>
#include <math.h>

#define D 256
#define NRULES 1024
#define TPB 8     // tokens per pass over a rule matrix
#define KMAX 16   // bucket stride; slot>=KMAX spills (P ~ 0 at Poisson(2))

// ---------------- prep: parallel histogram + compacted worklist, no scan ----------------
__global__ void prep_kernel(const int* __restrict__ token_ids,
                            const int* __restrict__ token_rules,
                            int ntok,
                            int* __restrict__ counts,    // [NRULES] pre-zeroed
                            int* __restrict__ bucket,    // [NRULES*KMAX]
                            int* __restrict__ worklist,  // [NRULES]
                            int* __restrict__ ctrl,      // [8] pre-zeroed: 0=nwork 1=qhead 2=nspill
                            int* __restrict__ spill) {   // [ntok]
    const int i = blockIdx.x * blockDim.x + threadIdx.x;
    if (i >= ntok) return;
    const int r = token_rules[token_ids[i]];
    const int slot = atomicAdd(&counts[r], 1);
    if (slot < KMAX) {
        bucket[r * KMAX + slot] = i;
        if (slot == 0) worklist[atomicAdd(&ctrl[0], 1)] = r;  // first touch -> one work item
    } else {
        spill[atomicAdd(&ctrl[2], 1)] = (r << 16) | i;        // tok<2048, r<1024 fit
    }
}

// ---------------- one TPB-pass over a rule matrix (R5 compute structure) ----------------
// 4 waves; wave owns 64-col quarter; rr=lane>>4 row subgroup; lockstep full rows.
template <int CR>
__device__ __forceinline__ void do_pass(
    const float* __restrict__ M,
    const float* __restrict__ hidden,
    const int* bucketrow,       // generic ptr (global bucket row, or LDS for spill)
    int base, int c,            // live tokens this pass, c <= CR
    int t, int wave, int lane, int rr, int col,
    float (*__restrict__ h_lds)[D], float* __restrict__ sq_lds,
    float* __restrict__ out)
{
    // stage h rows as float4: wave j stages token row j (64 lanes x 16B = 1KB)
    for (int j = wave; j < CR; j += 4) {
        float4 v = {0.f, 0.f, 0.f, 0.f};
        if (j < c)
            v = *reinterpret_cast<const float4*>(
                &hidden[(size_t)bucketrow[base + j] * D + (lane << 2)]);
        *reinterpret_cast<float4*>(&h_lds[j][lane << 2]) = v;
    }
    __syncthreads();

    float4 acc[CR];
    #pragma unroll
    for (int j = 0; j < CR; ++j) acc[j] = float4{0.f, 0.f, 0.f, 0.f};
    float sq = 0.f;

    #pragma unroll 8
    for (int i = 0; i < 64; ++i) {
        const int d = (i << 2) + rr;
        const float4 m = *reinterpret_cast<const float4*>(M + (size_t)d * D + col);
        sq = fmaf(m.x, m.x, fmaf(m.y, m.y, fmaf(m.z, m.z, fmaf(m.w, m.w, sq))));
        #pragma unroll
        for (int j = 0; j < CR; ++j) {
            const float h = h_lds[j][d];  // 4 addrs/wave, x16 broadcast — conflict-free
            acc[j].x = fmaf(h, m.x, acc[j].x);
            acc[j].y = fmaf(h, m.y, acc[j].y);
            acc[j].z = fmaf(h, m.z, acc[j].z);
            acc[j].w = fmaf(h, m.w, acc[j].w);
        }
    }

    // Frobenius: wave reduce, park per wave
    #pragma unroll
    for (int off = 32; off > 0; off >>= 1)
        sq += __shfl_down(sq, off, 64);
    if (lane == 0) sq_lds[wave] = sq;

    // butterfly over the 4 row-subgroups: every lane gets full column sums
    #pragma unroll
    for (int j = 0; j < CR; ++j) {
        #pragma unroll
        for (int mask = 16; mask < 64; mask <<= 1) {
            acc[j].x += __shfl_xor(acc[j].x, mask, 64);
            acc[j].y += __shfl_xor(acc[j].y, mask, 64);
            acc[j].z += __shfl_xor(acc[j].z, mask, 64);
            acc[j].w += __shfl_xor(acc[j].w, mask, 64);
        }
    }
    __syncthreads();

    const float fro2 = sq_lds[0] + sq_lds[1] + sq_lds[2] + sq_lds[3];
    const float inv  = 1.0f / fmaxf(sqrtf(fro2), 1e-12f);

    // subgroup (j&3) writes token j's quarter (16 lanes x 16B contiguous)
    #pragma unroll
    for (int j = 0; j < CR; ++j) {
        if (j < c && rr == (j & 3)) {
            const int tok = bucketrow[base + j];
            float4 o;
            o.x = acc[j].x * inv; o.y = acc[j].y * inv;
            o.z = acc[j].z * inv; o.w = acc[j].w * inv;
            *reinterpret_cast<float4*>(&out[(size_t)tok * D + col]) = o;
        }
    }
    __syncthreads();  // protect h_lds before restage / next item
}

// ---------------- process: 1024 resident 4-wave blocks consume rule queue ----------------
__global__ __launch_bounds__(256) void process_kernel(
    const float* __restrict__ hidden,     // [NTOK, D]
    const float* __restrict__ rules,      // [NRULES, D, D]
    const int*   __restrict__ counts,
    const int*   __restrict__ bucket,
    const int*   __restrict__ worklist,
    int*         __restrict__ ctrl,       // 0=nwork 1=qhead 2=nspill
    const int*   __restrict__ spill,
    float* __restrict__ out)
{
    const int t    = threadIdx.x;
    const int wave = t >> 6;
    const int lane = t & 63;
    const int rr   = lane >> 4;
    const int col  = (wave << 6) + ((lane & 15) << 2);

    __shared__ float h_lds[TPB][D];
    __shared__ float sq_lds[4];
    __shared__ int   sh_w;
    __shared__ int   stok[1];

    const int nwork = ctrl[0];

    for (;;) {
        if (t == 0) sh_w = atomicAdd(&ctrl[1], 1);
        __syncthreads();
        const int w = sh_w;
        if (w >= nwork) break;

        const int r   = worklist[w];
        const int cnt = min(counts[r], KMAX);
        const float* __restrict__ M = rules + (size_t)r * D * D;
        const int* brow = &bucket[r * KMAX];

        for (int base = 0; base < cnt; base += TPB) {
            const int c = min(cnt - base, TPB);
            switch ((c == 1) ? 1 : (c == 2) ? 2 : (c <= 4) ? 4 : 8) {
                case 1:  do_pass<1>(M, hidden, brow, base, c, t, wave, lane, rr, col, h_lds, sq_lds, out); break;
                case 2:  do_pass<2>(M, hidden, brow, base, c, t, wave, lane, rr, col, h_lds, sq_lds, out); break;
                case 4:  do_pass<4>(M, hidden, brow, base, c, t, wave, lane, rr, col, h_lds, sq_lds, out); break;
                default: do_pass<8>(M, hidden, brow, base, c, t, wave, lane, rr, col, h_lds, sq_lds, out); break;
            }
        }
    }

    // rare overflow tokens (count>KMAX): strided over blocks, single-token passes
    const int ns = ctrl[2];
    for (int k = blockIdx.x; k < ns; k += gridDim.x) {
        const int e = spill[k];
        if (t == 0) stok[0] = e & 0xFFFF;
        __syncthreads();
        do_pass<1>(rules + (size_t)(e >> 16) * D * D, hidden, stok, 0, 1,
                   t, wave, lane, rr, col, h_lds, sq_lds, out);
    }
}

// ---------------- launcher ----------------
extern "C" void kernel_launch(void* const* d_in, const int* in_sizes, int n_in,
                              void* d_out, int out_size, void* d_ws, size_t ws_size,
                              hipStream_t stream) {
    const float* hidden      = (const float*)d_in[0];
    const int*   token_ids   = (const int*)d_in[1];
    const float* rules       = (const float*)d_in[2];
    const int*   token_rules = (const int*)d_in[3];
    float*       out         = (float*)d_out;

    const int ntok = in_sizes[1];  // B*S

    int* ws       = (int*)d_ws;
    int* counts   = ws;                        // NRULES
    int* ctrl     = ws + NRULES;               // 8 ints: nwork, qhead, nspill
    int* bucket   = ws + NRULES + 8;           // NRULES*KMAX
    int* worklist = bucket + NRULES * KMAX;    // NRULES
    int* spill    = worklist + NRULES;         // ntok

    hipMemsetAsync(counts, 0, (NRULES + 8) * sizeof(int), stream);
    prep_kernel<<<(ntok + 255) / 256, 256, 0, stream>>>(
        token_ids, token_rules, ntok, counts, bucket, worklist, ctrl, spill);
    process_kernel<<<NRULES, 256, 0, stream>>>(
        hidden, rules, counts, bucket, worklist, ctrl, spill, out);
}